// Round 2
// baseline (65.045 us; speedup 1.0000x reference)
//
#include <hip/hip_runtime.h>
#include <math.h>

#define HH 512
#define WW 1024
#define RR 5
#define KK 11
#define TOPK 200
#define MAXC 16384
#define TILE 32
#define VH (TILE + 6)     // 38: vote region (NMS halo 3)
#define CRH (TILE + 16)   // 48: cr region (vote halo 5 on top of NMS halo 3)

// ws layout (bytes):
// [0..63]          : meta ints: meta[0]=cnt, meta[1]=Mtop, meta[2]=anyv
// [64 ..)          : cv float[MAXC]
// [64+4*MAXC ..)   : ci int[MAXC]
// [64+8*MAXC ..)   : selx float[TOPK], sely float[TOPK]

__global__ __launch_bounds__(256) void vote_nms_kernel(const float* __restrict__ cr,
                                                       float* __restrict__ cv,
                                                       int* __restrict__ ci,
                                                       int* __restrict__ meta, float ct) {
    __shared__ float sx[CRH][CRH + 1];
    __shared__ float sy[CRH][CRH + 1];
    __shared__ float sv[VH][VH + 1];
    const int bx = blockIdx.x * TILE, by = blockIdx.y * TILE;

    // Stage cr 48x48 region (origin by-8, bx-8), zero-padded outside image.
    for (int l = threadIdx.x; l < CRH * CRH; l += 256) {
        int ly = l / CRH, lx = l % CRH;
        int gy = by - 8 + ly, gx = bx - 8 + lx;
        bool ok = (gy >= 0) && (gy < HH) && (gx >= 0) && (gx < WW);
        sx[ly][lx] = ok ? cr[gy * WW + gx] : 0.0f;
        sy[ly][lx] = ok ? cr[HH * WW + gy * WW + gx] : 0.0f;
    }
    __syncthreads();

    // Vote on 38x38 (origin by-3, bx-3); +inf outside image (matches the
    // reference's inf-padded reduce_window). Halo votes recomputed here are
    // bit-identical to neighbor blocks' center votes (same fp32 op order).
    for (int l = threadIdx.x; l < VH * VH; l += 256) {
        int ly = l / VH, lx = l % VH;
        int gy = by - 3 + ly, gx = bx - 3 + lx;
        float res = INFINITY;
        if (gy >= 0 && gy < HH && gx >= 0 && gx < WW) {
            float err = 0.0f;
            // EXACT reference accumulation order: iy outer, ix inner, skip masked.
            #pragma unroll
            for (int iy = 0; iy < KK; ++iy) {
                #pragma unroll
                for (int ix = 0; ix < KK; ++ix) {
                    const int ox = ix - RR, oy = iy - RR;
                    if (ox * ox + oy * oy > RR * RR) continue;  // circle mask
                    float rx = sx[ly + iy][lx + ix];
                    float ry = sy[ly + iy][lx + ix];
                    float dx = (float)ox - rx;
                    float dy = (float)oy - ry;
                    err += sqrtf(dx * dx + dy * dy);
                }
            }
            res = err / 81.0f + 1.0f;
        }
        sv[ly][lx] = res;
    }
    __syncthreads();

    // 7x7 min-pool NMS from LDS; 4 pixels per thread.
    const int tx = threadIdx.x & 31, ty0 = threadIdx.x >> 5;
    for (int r = 0; r < 4; ++r) {
        int ty = ty0 + r * 8;
        float v = sv[ty + 3][tx + 3];
        float m = v;
        #pragma unroll
        for (int dy = 0; dy < 7; ++dy)
            #pragma unroll
            for (int dx = 0; dx < 7; ++dx)
                m = fminf(m, sv[ty + dy][tx + dx]);
        // keep iff local min of (clipped) 7x7 window AND strictly below CT
        if (v == m && v < ct) {
            int s = atomicAdd(&meta[0], 1);
            if (s < MAXC) { cv[s] = v; ci[s] = (by + ty) * WW + (bx + tx); }
        }
    }
}

__global__ __launch_bounds__(256) void select_kernel(const float* __restrict__ cv,
                                                     const int* __restrict__ ci,
                                                     int* __restrict__ meta,
                                                     float* __restrict__ selx,
                                                     float* __restrict__ sely,
                                                     float* __restrict__ out) {
    __shared__ float bv[256];
    __shared__ int bi[256];
    __shared__ int s_idx[TOPK];
    __shared__ float s_val[TOPK];
    const int tid = threadIdx.x;
    int M = meta[0];
    if (M > MAXC) M = MAXC;
    const int Mtop = (M < TOPK) ? M : TOPK;

    // k-th smallest by (val, idx) lexicographic = min over entries strictly
    // greater than the previously selected one (matches jax top_k tie-break).
    float lastv = -INFINITY;
    int lasti = -1;
    for (int k = 0; k < Mtop; ++k) {
        float bestv = INFINITY;
        int besti = 0x7fffffff;
        for (int j = tid; j < M; j += 256) {
            float v = cv[j];
            int i = ci[j];
            if (v > lastv || (v == lastv && i > lasti)) {
                if (v < bestv || (v == bestv && i < besti)) { bestv = v; besti = i; }
            }
        }
        bv[tid] = bestv; bi[tid] = besti;
        __syncthreads();
        for (int s = 128; s > 0; s >>= 1) {
            if (tid < s) {
                float ov = bv[tid + s]; int oi = bi[tid + s];
                if (ov < bv[tid] || (ov == bv[tid] && oi < bi[tid])) { bv[tid] = ov; bi[tid] = oi; }
            }
            __syncthreads();
        }
        lastv = bv[0]; lasti = bi[0];
        if (tid == 0) { s_val[k] = lastv; s_idx[k] = lasti; }
        __syncthreads();
    }

    if (tid == 0) {
        // fill remaining slots with the smallest non-candidate indices
        // (all non-candidates tie at -inf in top_k(-cand): ascending index)
        int cursor = 0;
        for (int k = Mtop; k < TOPK; ++k) {
            bool isc = true;
            while (isc) {
                isc = false;
                for (int j = 0; j < M; ++j) {
                    if (ci[j] == cursor) { isc = true; break; }
                }
                if (isc) cursor++;
            }
            s_idx[k] = cursor;
            s_val[k] = INFINITY;
            cursor++;
        }
        meta[1] = Mtop;
        meta[2] = (M > 0) ? 1 : 0;
    }
    __syncthreads();

    for (int k = tid; k < TOPK; k += 256) {
        int idx = s_idx[k];
        int cy = idx >> 10;          // idx / W
        int cx = idx & (WW - 1);     // idx % W
        out[HH * WW + 2 * k]     = (float)cy;
        out[HH * WW + 2 * k + 1] = (float)cx;
        bool valid = (k < Mtop);
        out[HH * WW + 2 * TOPK + k] = valid ? s_val[k] : 0.0f;
        selx[k] = (float)cx;
        sely[k] = (float)cy;
    }
}

__global__ __launch_bounds__(256) void inst_kernel(const float* __restrict__ fg,
                                                   const float* __restrict__ cr,
                                                   const float* __restrict__ selx,
                                                   const float* __restrict__ sely,
                                                   const int* __restrict__ meta,
                                                   float* __restrict__ out) {
    int pix = blockIdx.x * 256 + threadIdx.x;
    int y = pix >> 10, x = pix & (WW - 1);
    const int Mtop = meta[1];
    const int anyv = meta[2];
    float res = 0.0f;
    if (anyv && fg[pix] >= 0.5f) {
        float px = (float)(x + 1) - cr[pix];
        float py = (float)(y + 1) - cr[HH * WW + pix];
        float best = INFINITY;
        int bk = 0;
        for (int k = 0; k < Mtop; ++k) {
            float ddx = px - selx[k];
            float ddy = py - sely[k];
            float d = ddx * ddx + ddy * ddy;
            if (d < best) { best = d; bk = k; }  // strict < keeps first occurrence
        }
        res = (float)(bk + 1);
    }
    out[pix] = res;
}

extern "C" void kernel_launch(void* const* d_in, const int* in_sizes, int n_in,
                              void* d_out, int out_size, void* d_ws, size_t ws_size,
                              hipStream_t stream) {
    const float* fg = (const float*)d_in[0];
    const float* cr = (const float*)d_in[1];
    float* out = (float*)d_out;

    char* ws = (char*)d_ws;
    int* meta = (int*)ws;
    float* cv = (float*)(ws + 64);
    int* ci = (int*)(ws + 64 + 4 * MAXC);
    float* selx = (float*)(ws + 64 + 8 * MAXC);
    float* sely = selx + TOPK;

    // CENTER_THRESH = mean circle distance + 0.5 (double precision host calc;
    // ~1e-7 from the reference's fp32 value, margin to nearest vote is ~0.3)
    double s = 0.0;
    int n = 0;
    for (int iy = 0; iy < KK; ++iy)
        for (int ix = 0; ix < KK; ++ix) {
            double dx = ix - RR, dy = iy - RR;
            double d = sqrt(dx * dx + dy * dy);
            if (d <= (double)RR) { s += d; n++; }
        }
    float ct = (float)(s / n + 0.5);

    hipMemsetAsync(d_ws, 0, 64, stream);

    dim3 vgrid(WW / TILE, HH / TILE);   // 32 x 16 = 512 blocks
    vote_nms_kernel<<<vgrid, 256, 0, stream>>>(cr, cv, ci, meta, ct);
    select_kernel<<<1, 256, 0, stream>>>(cv, ci, meta, selx, sely, out);
    inst_kernel<<<(HH * WW) / 256, 256, 0, stream>>>(fg, cr, selx, sely, meta, out);
}

// Round 3
// 39.734 us; speedup vs baseline: 1.6370x; 1.6370x over previous
//
#include <hip/hip_runtime.h>
#include <math.h>

#define HH 512
#define WW 1024
#define RR 5
#define KK 11
#define TOPK 200
#define MAXC 16384

#define BW 64          // vote tile width
#define BH 8           // vote tile height
#define TT 2           // outputs per thread (column)
#define SROWS (BH + 10)  // 18 staged rows
#define SCOLS (BW + 10)  // 74 staged cols

// ws layout (bytes):
// [0..63]          : meta ints: meta[0]=cnt, meta[1]=Mtop, meta[2]=anyv
// [64 ..)          : vote float[H*W]
// [64+4*HW ..)     : cv float[MAXC]
// [.. +4*MAXC ..)  : ci int[MAXC]
// [.. +4*MAXC ..)  : selx float[TOPK], sely float[TOPK]

__global__ __launch_bounds__(256) void vote_kernel(const float* __restrict__ cr,
                                                   float* __restrict__ vote,
                                                   int* __restrict__ meta) {
    __shared__ float2 s[SROWS][BW + 16];   // padded to 80 float2/row
    const int tid = threadIdx.x;
    const int bx = blockIdx.x * BW, by = blockIdx.y * BH;

    if (bx == 0 && by == 0 && tid == 0) { meta[0] = 0; meta[1] = 0; meta[2] = 0; }

    // Stage cr (SROWS x SCOLS) region, origin (by-5, bx-5), zero-padded.
    for (int l = tid; l < SROWS * SCOLS; l += 256) {
        int r = l / SCOLS, c = l % SCOLS;
        int gy = by - 5 + r, gx = bx - 5 + c;
        bool ok = (gy >= 0) && (gy < HH) && (gx >= 0) && (gx < WW);
        float vx = ok ? cr[gy * WW + gx] : 0.0f;
        float vy = ok ? cr[HH * WW + gy * WW + gx] : 0.0f;
        s[r][c] = make_float2(vx, vy);
    }
    __syncthreads();

    const int x = tid & 63;        // 0..63 within tile
    const int yt = tid >> 6;       // 0..3 -> output rows yt*2, yt*2+1
    // 4 independent accumulator chains (reassociated sum: safe — vote
    // perturbation ~1e-5 vs 0.3 margin to CENTER_THRESH; NMS equality only
    // compares values computed here with identical op order).
    float a0 = 0.f, b0 = 0.f, a1 = 0.f, b1 = 0.f;

    #pragma unroll
    for (int rr = 0; rr <= TT + 9; ++rr) {          // LDS row offset 0..11
        #pragma unroll
        for (int ix = 0; ix < KK; ++ix) {
            const int ox = ix - 5;
            float2 v = s[yt * TT + rr][x + ix];
            {   // t = 0 : oy = rr - 5
                const int oy = rr - 5;
                if (oy >= -RR && oy <= RR && ox * ox + oy * oy <= RR * RR) {
                    float dx = (float)ox - v.x, dy = (float)oy - v.y;
                    float sv = __builtin_amdgcn_sqrtf(dx * dx + dy * dy);
                    if (ix & 1) b0 += sv; else a0 += sv;
                }
            }
            {   // t = 1 : oy = rr - 6
                const int oy = rr - 6;
                if (oy >= -RR && oy <= RR && ox * ox + oy * oy <= RR * RR) {
                    float dx = (float)ox - v.x, dy = (float)oy - v.y;
                    float sv = __builtin_amdgcn_sqrtf(dx * dx + dy * dy);
                    if (ix & 1) b1 += sv; else a1 += sv;
                }
            }
        }
    }
    const int y0 = by + yt * TT;
    vote[y0 * WW + bx + x]       = (a0 + b0) / 81.0f + 1.0f;
    vote[(y0 + 1) * WW + bx + x] = (a1 + b1) / 81.0f + 1.0f;
}

__global__ __launch_bounds__(256) void nms_kernel(const float* __restrict__ vote,
                                                  float* __restrict__ cv, int* __restrict__ ci,
                                                  int* __restrict__ meta, float ct) {
    int pix = blockIdx.x * 256 + threadIdx.x;
    int y = pix >> 10, x = pix & (WW - 1);
    float v = vote[pix];
    float m = v;
    // index-clamp == inf-padding for a min-pool (duplicated edge values
    // cannot change the min)
    #pragma unroll
    for (int dy = -3; dy <= 3; ++dy) {
        int yy = min(max(y + dy, 0), HH - 1);
        const float* row = vote + yy * WW;
        #pragma unroll
        for (int dx = -3; dx <= 3; ++dx) {
            int xx = min(max(x + dx, 0), WW - 1);
            m = fminf(m, row[xx]);
        }
    }
    if (v == m && v < ct) {
        int s = atomicAdd(&meta[0], 1);
        if (s < MAXC) { cv[s] = v; ci[s] = pix; }
    }
}

__global__ __launch_bounds__(256) void select_kernel(const float* __restrict__ cv,
                                                     const int* __restrict__ ci,
                                                     int* __restrict__ meta,
                                                     float* __restrict__ selx,
                                                     float* __restrict__ sely,
                                                     float* __restrict__ out) {
    __shared__ float bv[256];
    __shared__ int bi[256];
    __shared__ int s_idx[TOPK];
    __shared__ float s_val[TOPK];
    const int tid = threadIdx.x;
    int M = meta[0];
    if (M > MAXC) M = MAXC;
    const int Mtop = (M < TOPK) ? M : TOPK;

    // k-th smallest by (val, idx) lexicographic = min over entries strictly
    // greater than the previously selected one (matches jax top_k tie-break).
    float lastv = -INFINITY;
    int lasti = -1;
    for (int k = 0; k < Mtop; ++k) {
        float bestv = INFINITY;
        int besti = 0x7fffffff;
        for (int j = tid; j < M; j += 256) {
            float v = cv[j];
            int i = ci[j];
            if (v > lastv || (v == lastv && i > lasti)) {
                if (v < bestv || (v == bestv && i < besti)) { bestv = v; besti = i; }
            }
        }
        bv[tid] = bestv; bi[tid] = besti;
        __syncthreads();
        for (int s = 128; s > 0; s >>= 1) {
            if (tid < s) {
                float ov = bv[tid + s]; int oi = bi[tid + s];
                if (ov < bv[tid] || (ov == bv[tid] && oi < bi[tid])) { bv[tid] = ov; bi[tid] = oi; }
            }
            __syncthreads();
        }
        lastv = bv[0]; lasti = bi[0];
        if (tid == 0) { s_val[k] = lastv; s_idx[k] = lasti; }
        __syncthreads();
    }

    if (tid == 0) {
        // fill remaining slots with the smallest non-candidate indices
        // (all non-candidates tie at -inf in top_k(-cand): ascending index)
        int cursor = 0;
        for (int k = Mtop; k < TOPK; ++k) {
            bool isc = true;
            while (isc) {
                isc = false;
                for (int j = 0; j < M; ++j) {
                    if (ci[j] == cursor) { isc = true; break; }
                }
                if (isc) cursor++;
            }
            s_idx[k] = cursor;
            s_val[k] = INFINITY;
            cursor++;
        }
        meta[1] = Mtop;
        meta[2] = (M > 0) ? 1 : 0;
    }
    __syncthreads();

    for (int k = tid; k < TOPK; k += 256) {
        int idx = s_idx[k];
        int cy = idx >> 10;          // idx / W
        int cx = idx & (WW - 1);     // idx % W
        out[HH * WW + 2 * k]     = (float)cy;
        out[HH * WW + 2 * k + 1] = (float)cx;
        bool valid = (k < Mtop);
        out[HH * WW + 2 * TOPK + k] = valid ? s_val[k] : 0.0f;
        selx[k] = (float)cx;
        sely[k] = (float)cy;
    }
}

__global__ __launch_bounds__(256) void inst_kernel(const float* __restrict__ fg,
                                                   const float* __restrict__ cr,
                                                   const float* __restrict__ selx,
                                                   const float* __restrict__ sely,
                                                   const int* __restrict__ meta,
                                                   float* __restrict__ out) {
    int pix = blockIdx.x * 256 + threadIdx.x;
    int y = pix >> 10, x = pix & (WW - 1);
    const int Mtop = meta[1];
    const int anyv = meta[2];
    float res = 0.0f;
    if (anyv && fg[pix] >= 0.5f) {
        float px = (float)(x + 1) - cr[pix];
        float py = (float)(y + 1) - cr[HH * WW + pix];
        float best = INFINITY;
        int bk = 0;
        for (int k = 0; k < Mtop; ++k) {
            float ddx = px - selx[k];
            float ddy = py - sely[k];
            float d = ddx * ddx + ddy * ddy;
            if (d < best) { best = d; bk = k; }  // strict < keeps first occurrence
        }
        res = (float)(bk + 1);
    }
    out[pix] = res;
}

extern "C" void kernel_launch(void* const* d_in, const int* in_sizes, int n_in,
                              void* d_out, int out_size, void* d_ws, size_t ws_size,
                              hipStream_t stream) {
    const float* fg = (const float*)d_in[0];
    const float* cr = (const float*)d_in[1];
    float* out = (float*)d_out;

    char* ws = (char*)d_ws;
    int* meta = (int*)ws;
    float* vote = (float*)(ws + 64);
    float* cv = (float*)(ws + 64 + 4 * HH * WW);
    int* ci = (int*)(ws + 64 + 4 * HH * WW + 4 * MAXC);
    float* selx = (float*)(ws + 64 + 4 * HH * WW + 8 * MAXC);
    float* sely = selx + TOPK;

    // CENTER_THRESH = mean circle distance + 0.5
    double s = 0.0;
    int n = 0;
    for (int iy = 0; iy < KK; ++iy)
        for (int ix = 0; ix < KK; ++ix) {
            double dx = ix - RR, dy = iy - RR;
            double d = sqrt(dx * dx + dy * dy);
            if (d <= (double)RR) { s += d; n++; }
        }
    float ct = (float)(s / n + 0.5);

    dim3 vgrid(WW / BW, HH / BH);   // 16 x 64 = 1024 blocks
    vote_kernel<<<vgrid, 256, 0, stream>>>(cr, vote, meta);
    nms_kernel<<<(HH * WW) / 256, 256, 0, stream>>>(vote, cv, ci, meta, ct);
    select_kernel<<<1, 256, 0, stream>>>(cv, ci, meta, selx, sely, out);
    inst_kernel<<<(HH * WW) / 256, 256, 0, stream>>>(fg, cr, selx, sely, meta, out);
}